// Round 13
// baseline (242.212 us; speedup 1.0000x reference)
//
#include <hip/hip_runtime.h>
#include <cstdint>

// Problem constants (from reference setup_inputs): N=M=8192, F=H=512, V=3.
#define NROWS 8192
#define MDIM  8192
#define FDIM  512
#define HDIM  512
#define GWSPLIT 8            // 24 K-slices = 3 per XCD
#define NOMASK 0x7fffffff

typedef _Float16 f16x8_t __attribute__((ext_vector_type(8)));
typedef float    f32x4_t __attribute__((ext_vector_type(4)));
typedef int      i32x4_t __attribute__((ext_vector_type(4)));

__device__ __forceinline__ unsigned short f2h(float f) {
    return __builtin_bit_cast(unsigned short, (_Float16)f);
}
__device__ __forceinline__ float h2f(unsigned short u) {
    return (float)__builtin_bit_cast(_Float16, u);
}

// async global->LDS, 16B per lane; LDS dest = uniform base + lane*16
__device__ __forceinline__ void g2l16(const unsigned short* g, unsigned short* l) {
    __builtin_amdgcn_global_load_lds(
        (const __attribute__((address_space(1))) void*)g,
        (__attribute__((address_space(3))) void*)l, 16, 0, 0);
}

// ---- one-dispatch prep: z=0..2 view cvt+transpose, z=3 cz cvt, z=4 Wq/Wk cvt ----
__global__ void k_prep(const float* __restrict__ zs,
                       unsigned short* __restrict__ zn,       // X_h + MF (row-major views)
                       unsigned short* __restrict__ zt, long tV,  // kzT upper half
                       const float* __restrict__ cz, unsigned short* __restrict__ cz_h,
                       const float* __restrict__ Wq, unsigned short* __restrict__ wq_h,
                       const float* __restrict__ Wk, unsigned short* __restrict__ wk_h) {
    const long MF = (long)MDIM * FDIM;
    int z = blockIdx.z;
    if (z < 3) {
        const float* src = zs + (long)z * MF;
        unsigned short* dn = zn + (long)z * MF;
        unsigned short* dt = zt + (long)z * tV;
        __shared__ unsigned short t[32][33];
        int c0 = blockIdx.x * 32, r0 = blockIdx.y * 32;
        #pragma unroll
        for (int k = 0; k < 32; k += 8) {
            unsigned short b = f2h(src[(size_t)(r0 + threadIdx.y + k) * FDIM + c0 + threadIdx.x]);
            dn[(size_t)(r0 + threadIdx.y + k) * FDIM + c0 + threadIdx.x] = b;
            t[threadIdx.y + k][threadIdx.x] = b;
        }
        __syncthreads();
        #pragma unroll
        for (int k = 0; k < 32; k += 8)
            dt[(size_t)(c0 + threadIdx.y + k) * MDIM + r0 + threadIdx.x] =
                t[threadIdx.x][threadIdx.y + k];
    } else {
        int tid = threadIdx.y * 32 + threadIdx.x;             // 0..255
        int b = blockIdx.y * gridDim.x + blockIdx.x;          // 0..4095
        if (z == 3) {
            int i = b * 256 + tid;                            // NROWS*FDIM/4 = 1,048,576
            float4 f = ((const float4*)cz)[i];
            ushort4 u;
            u.x = f2h(f.x); u.y = f2h(f.y); u.z = f2h(f.z); u.w = f2h(f.w);
            ((ushort4*)cz_h)[i] = u;
        } else if (b < 512) {
            const float4* s = (b < 256) ? (const float4*)Wq : (const float4*)Wk;
            ushort4* d = (b < 256) ? (ushort4*)wq_h : (ushort4*)wk_h;
            int i = (b & 255) * 256 + tid;                    // 65536 per matrix
            float4 f = s[i];
            ushort4 u;
            u.x = f2h(f.x); u.y = f2h(f.y); u.z = f2h(f.z); u.w = f2h(f.w);
            d[i] = u;
        }
    }
}

// ---- reduce GWSPLIT fp16 split-K partials; rows<512 -> G fp16 [v][512][512],
//      rows>=512 -> Bfin fp16 [512][1536] (col = v*512+h). Zeroes n2. ----
__global__ void k_rsplit(const unsigned short* __restrict__ GWp,
                         unsigned short* __restrict__ G,
                         unsigned short* __restrict__ Bfin,
                         float* __restrict__ n2, int n) {
    int i = blockIdx.x * blockDim.x + threadIdx.x;
    if (i >= n) return;
    if (i < 3 * NROWS) n2[i] = 0.f;
    int v = i / (1024 * 512);
    int rc = i - v * (1024 * 512);
    int row = rc >> 9, col = rc & 511;
    const unsigned short* p = GWp + (size_t)v * GWSPLIT * 1024 * 512 + rc;
    float s = 0.f;
    #pragma unroll
    for (int sl = 0; sl < GWSPLIT; ++sl) s += h2f(p[(size_t)sl * 1024 * 512]);
    if (row < 512) G[((size_t)v * 512 + row) * 512 + col] = f2h(s);
    else Bfin[(size_t)(row - 512) * 1536 + v * 512 + col] = f2h(s);
}

// ---------------- fp16 GEMM, C[row][col] = sum_k A[row][k]*B[col][k] ----------------
// Tile: 128 x (JT*32); JT=4 (modes 0/3/4) or 2 (MODE2). BK=128 ALL MODES (r12:
// per-iteration fixed overhead dominates the K-loop — halve iters, not bytes).
// LDS: 64KB (JT=4) / 48KB (MODE2). 256 threads = 4 waves, each 4 x JT MFMA tiles.
// 1D grid + XCD-aware decode (xcd = blockIdx.x & 7): blocks sharing an operand
// panel / K-slice land on ONE XCD so its 4MB L2 serves the re-reads.
// LDS XOR-swizzle (CPR=16): slot (row,c) holds global chunk (c&8)|((c^row)&7)
// -> fragment ds_read_b128 chunk (kk*4+quad)^(r&7) is 2-way only = free.
// MODE 0: 1024 blk, K=512 (4 iters). panel p=(z,y) on xcd p%8; x in-xcd.
//         z=0: Cb=fp16(elu) row-major (q). z>=1: k^T via per-wave LDS transpose.
// MODE 2: 512 blk, 128x64 tile, K=1536 (12 iters). q-panel y on xcd y%8.
//         Cf = CZ + acc, A-frags scaled per (row, view=k/512) from norms.
// MODE 3: 768 blk, K=1024/slice (8 iters). K-slice s on xcd s%8 (2MB < L2).
//         Cb16 partial[s] = fp16(acc). view=s>>3, kbeg=(s&7)*K.
// MODE 4: 768 blk, K=512 (4 iters). q-panel y on xcd y%8; 12 (x,v) co-located.
//         atomicAdd(norms[view][row], sum_col acc*Q[row][col]).
template<int MODE>
__global__ __launch_bounds__(256, 4)
void k_gemm_bt(const unsigned short* __restrict__ A, int lda, long aV, int akmask,
               const unsigned short* __restrict__ B, int ldb, long bV,
               int K,
               unsigned short* __restrict__ Cb, long cbV,
               float* __restrict__ Cf, int ldc, long cfV,
               float* __restrict__ norms,
               const unsigned short* __restrict__ Q,
               const float* __restrict__ CZ,
               const unsigned short* __restrict__ B2,
               unsigned short* __restrict__ Cb2) {
    constexpr int JT  = (MODE == 2) ? 2 : 4;     // j-tiles per wave (cols = JT*32)
    constexpr int BK  = 128;                     // K per tile
    constexpr int RPC = 4;                       // rows per g2l16 call (512B / 128B row)
    constexpr int ACALLS = 8;                    // A staging calls per wave
    constexpr int BCALLS = JT * 2;               // B staging calls per wave
    // ---- XCD-aware index decode ----
    const int b = blockIdx.x;
    const int xcd = b & 7, ib = b >> 3;
    int bx, by, z, kbeg = 0, pidx = 0;
    if (MODE == 0) {            // 1024: panels p=0..255 (z=p>>6, y=p&63), x in-xcd
        int p = xcd + 8 * (ib >> 2);
        bx = ib & 3; z = p >> 6; by = p & 63;
    } else if (MODE == 3) {     // 768: slices s=0..23 on xcd s%8, 32 (x,y) in-xcd
        int s = xcd + 8 * (ib >> 5);
        int xy = ib & 31;
        bx = xy & 3; by = xy >> 2;
        z = s >> 3; kbeg = (s & 7) * K; pidx = s;
    } else if (MODE == 4) {     // 768: q-panels y=0..63 on xcd y%8, 12 (x,v) in-xcd
        by = xcd + 8 * (ib / 12);
        int r = ib % 12;
        bx = r & 3; z = r >> 2;
    } else {                    // MODE 2, 512: q-panels y=0..63 on xcd y%8, 8 x in-xcd
        by = xcd + 8 * (ib >> 3);
        bx = ib & 7; z = 0;
    }

    A += (long)z * aV;
    const unsigned short* Bp = (MODE == 0 && z > 0) ? B2 : B;
    Bp += (long)z * bV;

    __shared__ unsigned short S[128 * 128 + (JT * 32) * 128];   // 64KB / 48KB
    unsigned short* As = S;
    unsigned short* Bs = S + 128 * BK;
    const int tid  = threadIdx.x;
    const int lane = tid & 63;
    const int w    = tid >> 6;
    const int wr   = w >> 1, wc = w & 1;
    const int row0 = by * 128;
    const int col0 = bx * (JT * 32);
    const int quad = lane >> 4;
    const int l15  = lane & 15;
    const int srow = lane >> 4;                 // row within a staging call (0..3)
    const int lchunk = lane & 15;               // 16B chunk within row

    // MODE2: per-row per-view scales for A fragments
    _Float16 sch[3][4];
    if (MODE == 2) {
        #pragma unroll
        for (int v = 0; v < 3; ++v)
            #pragma unroll
            for (int i = 0; i < 4; ++i) {
                int row = row0 + wr * 64 + i * 16 + l15;
                float nn = norms[v * NROWS + row];
                float s = 1.f / fmaxf(sqrtf(fmaxf(nn, 0.f)), 1e-12f);
                sch[v][i] = (_Float16)fminf(s, 60000.f);
            }
    }

    f32x4_t acc[4][JT] = {};

    for (int k0 = kbeg; k0 < kbeg + K; k0 += BK) {
        __syncthreads();
        const int ka = k0 & akmask;
        #pragma unroll
        for (int c = 0; c < ACALLS; ++c) {
            int row = (w * ACALLS + c) * RPC + srow;          // 0..127
            int scol = ((lchunk & 8) | ((lchunk ^ row) & 7)) * 8;
            g2l16(A + (size_t)(row0 + row) * lda + ka + scol,
                  &As[(w * ACALLS + c) * 512]);
        }
        #pragma unroll
        for (int c = 0; c < BCALLS; ++c) {
            int row = (w * BCALLS + c) * RPC + srow;          // 0..(JT*32-1)
            int scol = ((lchunk & 8) | ((lchunk ^ row) & 7)) * 8;
            g2l16(Bp + (size_t)(col0 + row) * ldb + k0 + scol,
                  &Bs[(w * BCALLS + c) * 512]);
        }
        asm volatile("s_waitcnt vmcnt(0)" ::: "memory");
        __syncthreads();
        #pragma unroll
        for (int kk = 0; kk < BK / 32; ++kk) {
            f16x8_t af[4], bfr[JT];
            #pragma unroll
            for (int i = 0; i < 4; ++i) {
                int r = wr * 64 + i * 16 + l15;
                int ch = (kk * 4 + quad) ^ (r & 7);           // bit3 untouched
                af[i] = __builtin_bit_cast(f16x8_t,
                        *(const i32x4_t*)&As[r * BK + ch * 8]);
            }
            if (MODE == 2) {
                int vw = k0 >> 9;
                #pragma unroll
                for (int i = 0; i < 4; ++i) af[i] = af[i] * sch[vw][i];
            }
            #pragma unroll
            for (int j = 0; j < JT; ++j) {
                int r = wc * (JT * 16) + j * 16 + l15;
                int ch = (kk * 4 + quad) ^ (r & 7);
                bfr[j] = __builtin_bit_cast(f16x8_t,
                        *(const i32x4_t*)&Bs[r * BK + ch * 8]);
            }
            #pragma unroll
            for (int i = 0; i < 4; ++i)
                #pragma unroll
                for (int j = 0; j < JT; ++j)
                    acc[i][j] = __builtin_amdgcn_mfma_f32_16x16x32_f16(
                        af[i], bfr[j], acc[i][j], 0, 0, 0);
        }
    }

    // C/D layout (m89-verified): col = lane&15, row = (lane>>4)*4 + reg
    if (MODE == 0) {
        if (z == 0) {
            #pragma unroll
            for (int i = 0; i < 4; ++i) {
                int rb = row0 + wr * 64 + i * 16 + quad * 4;
                #pragma unroll
                for (int j = 0; j < 4; ++j) {
                    int col = col0 + wc * 64 + j * 16 + l15;
                    #pragma unroll
                    for (int r = 0; r < 4; ++r) {
                        float v = acc[i][j][r];
                        v = v > 0.f ? v : expm1f(v);
                        Cb[(size_t)(rb + r) * ldc + col] = f2h(v);
                    }
                }
            }
        } else {
            // transposed epilogue: wave-local 64x64 tile -> LDS (XOR swizzle) -> k^T
            __syncthreads();               // all waves done reading As/Bs
            unsigned short* T = S + w * 4096;   // 8KB slab per wave
            #pragma unroll
            for (int i = 0; i < 4; ++i)
                #pragma unroll
                for (int j = 0; j < 4; ++j) {
                    int ct = j * 16 + l15;
                    #pragma unroll
                    for (int r = 0; r < 4; ++r) {
                        int rt = i * 16 + quad * 4 + r;
                        float v = acc[i][j][r];
                        v = v > 0.f ? v : expm1f(v);
                        T[ct * 64 + (rt ^ ((ct & 7) << 3))] = f2h(v);
                    }
                }
            unsigned short* dst = Cb2 + (long)(z - 1) * cbV;
            #pragma unroll
            for (int it = 0; it < 8; ++it) {
                int c  = it * 8 + (lane >> 3);
                int rg = (lane & 7) * 8;
                i32x4_t val = *(const i32x4_t*)&T[c * 64 + (rg ^ ((c & 7) << 3))];
                *(i32x4_t*)&dst[(size_t)(col0 + wc * 64 + c) * MDIM
                                + row0 + wr * 64 + rg] = val;
            }
        }
    } else if (MODE == 2) {
        #pragma unroll
        for (int i = 0; i < 4; ++i) {
            #pragma unroll
            for (int r = 0; r < 4; ++r) {
                int row = row0 + wr * 64 + i * 16 + quad * 4 + r;
                #pragma unroll
                for (int j = 0; j < JT; ++j) {
                    int col = col0 + wc * (JT * 16) + j * 16 + l15;
                    Cf[(size_t)row * ldc + col] =
                        CZ[(size_t)row * ldc + col] + acc[i][j][r];
                }
            }
        }
    } else if (MODE == 3) {
        unsigned short* C = Cb + (long)pidx * cbV;   // fp16 partial slab
        #pragma unroll
        for (int i = 0; i < 4; ++i) {
            int rb = row0 + wr * 64 + i * 16 + quad * 4;
            #pragma unroll
            for (int j = 0; j < 4; ++j) {
                int col = col0 + wc * 64 + j * 16 + l15;
                #pragma unroll
                for (int r = 0; r < 4; ++r)
                    C[(size_t)(rb + r) * ldc + col] = f2h(acc[i][j][r]);
            }
        }
    } else if (MODE == 4) {
        float* nptr = norms + (long)z * NROWS;
        float rs[4][4] = {};
        #pragma unroll
        for (int i = 0; i < 4; ++i) {
            #pragma unroll
            for (int j = 0; j < 4; ++j) {
                #pragma unroll
                for (int r = 0; r < 4; ++r) {
                    int rb = row0 + wr * 64 + i * 16 + quad * 4;
                    int col = col0 + wc * 64 + j * 16 + l15;
                    rs[i][r] += acc[i][j][r] * h2f(Q[(size_t)(rb + r) * ldc + col]);
                }
            }
        }
        #pragma unroll
        for (int i = 0; i < 4; ++i)
            #pragma unroll
            for (int r = 0; r < 4; ++r) {
                float v = rs[i][r];
                v += __shfl_xor(v, 1);
                v += __shfl_xor(v, 2);
                v += __shfl_xor(v, 4);
                v += __shfl_xor(v, 8);
                if (l15 == 0)
                    atomicAdd(&nptr[row0 + wr * 64 + i * 16 + quad * 4 + r], v);
            }
    }
}

extern "C" void kernel_launch(void* const* d_in, const int* in_sizes, int n_in,
                              void* d_out, int out_size, void* d_ws, size_t ws_size,
                              hipStream_t stream) {
    const float* cz = (const float*)d_in[0];
    const float* zs = (const float*)d_in[1];
    const float* Wq = (const float*)d_in[2];
    const float* Wk = (const float*)d_in[3];
    float* out = (float*)d_out;

    char* ws = (char*)d_ws;
    size_t off = 0;
    auto alloc = [&](size_t bytes) -> void* {
        void* p = ws + off;
        off += (bytes + 255) & ~(size_t)255;
        return p;
    };
    const long MF = (long)MDIM * FDIM;   // 8192*512
    const long KZ = (long)1024 * MDIM;   // per-view kzT stride
    const long PS = (long)1024 * 512;    // partial slab elems

    unsigned short* X_h   = (unsigned short*)alloc((size_t)4 * MF * 2);          // 32 MB: [cz; zv0..2]
    unsigned short* wq_h  = (unsigned short*)alloc((size_t)HDIM * FDIM * 2);
    unsigned short* wk_h  = (unsigned short*)alloc((size_t)HDIM * FDIM * 2);
    unsigned short* q_h   = (unsigned short*)alloc((size_t)NROWS * HDIM * 2);    // 8 MB
    unsigned short* kzT   = (unsigned short*)alloc((size_t)3 * KZ * 2);          // 48 MB: [kT; zvT]/view
    unsigned short* GWp   = (unsigned short*)alloc((size_t)3 * GWSPLIT * PS * 2); // 24 MB fp16 partials
    unsigned short* G     = (unsigned short*)alloc((size_t)3 * 512 * 512 * 2);
    unsigned short* Bfin  = (unsigned short*)alloc((size_t)512 * 1536 * 2);
    float* n2             = (float*)alloc((size_t)3 * NROWS * 4);

    // 1: all input converts + zvT transpose (z=0..2 views, z=3 cz, z=4 Wq/Wk)
    k_prep<<<dim3(FDIM / 32, MDIM / 32, 5), dim3(32, 8), 0, stream>>>(
        zs, X_h + MF, kzT + (size_t)512 * MDIM, KZ,
        cz, X_h, Wq, wq_h, Wk, wk_h);

    // 2: z=0: q = elu(cz@Wq^T) -> q_h; z=1..3: kT_v = elu(zv@Wk^T)^T -> kzT lower half
    k_gemm_bt<0><<<dim3(1024), 256, 0, stream>>>(
        X_h, FDIM, MF, NOMASK, wq_h, FDIM, 0, FDIM,
        q_h, KZ, nullptr, HDIM, 0, nullptr, nullptr, nullptr, wk_h, kzT);

    // 3: [G_v; Wvt_v] = [kT_v; zvT_v] @ kT_v^T, 24 fp16 split-K partial slabs
    k_gemm_bt<3><<<dim3(768), 256, 0, stream>>>(
        kzT, MDIM, KZ, NOMASK, kzT, MDIM, KZ, MDIM / GWSPLIT,
        GWp, PS, nullptr, 512, 0, nullptr, nullptr, nullptr, nullptr, nullptr);

    // 4: reduce partials -> G fp16, Bfin fp16; zero n2
    k_rsplit<<<dim3(3 * 1024 * 512 / 256), 256, 0, stream>>>(
        GWp, G, Bfin, n2, 3 * 1024 * 512);

    // 5: n2_v[r] = (q G_v^T)_r . q_r
    k_gemm_bt<4><<<dim3(768), 256, 0, stream>>>(
        q_h, HDIM, 0, NOMASK, G, HDIM, (long)512 * 512, HDIM,
        nullptr, 0, nullptr, HDIM, 0, n2, q_h, nullptr, nullptr, nullptr);

    // 6: out = cz + sum_v s_v(row) * (q @ Wvt_v^T)   (K=1536, BK=128, A wraps k&511,
    //    per-view per-row scale fused into A fragments; 128x64 tiles, 512 blocks)
    k_gemm_bt<2><<<dim3(512), 256, 0, stream>>>(
        q_h, HDIM, 0, 511, Bfin, 1536, 0, 1536,
        nullptr, 0, out, FDIM, 0, n2, nullptr, cz, nullptr, nullptr);
}

// Round 14
// 220.721 us; speedup vs baseline: 1.0974x; 1.0974x over previous
//
#include <hip/hip_runtime.h>
#include <cstdint>

// Problem constants (from reference setup_inputs): N=M=8192, F=H=512, V=3.
#define NROWS 8192
#define MDIM  8192
#define FDIM  512
#define HDIM  512
#define GWSPLIT 8            // 24 K-slices = 3 per XCD
#define NOMASK 0x7fffffff

typedef _Float16 f16x8_t __attribute__((ext_vector_type(8)));
typedef float    f32x4_t __attribute__((ext_vector_type(4)));
typedef int      i32x4_t __attribute__((ext_vector_type(4)));

__device__ __forceinline__ unsigned short f2h(float f) {
    return __builtin_bit_cast(unsigned short, (_Float16)f);
}
__device__ __forceinline__ float h2f(unsigned short u) {
    return (float)__builtin_bit_cast(_Float16, u);
}

// async global->LDS, 16B per lane; LDS dest = uniform base + lane*16
__device__ __forceinline__ void g2l16(const unsigned short* g, unsigned short* l) {
    __builtin_amdgcn_global_load_lds(
        (const __attribute__((address_space(1))) void*)g,
        (__attribute__((address_space(3))) void*)l, 16, 0, 0);
}

// ---- one-dispatch prep: z=0..2 view cvt+transpose (float4/ushort4 vectorized),
//      z=3 cz cvt, z=4 Wq/Wk cvt ----
__global__ void k_prep(const float* __restrict__ zs,
                       unsigned short* __restrict__ zn,       // X_h + MF (row-major views)
                       unsigned short* __restrict__ zt, long tV,  // kzT upper half
                       const float* __restrict__ cz, unsigned short* __restrict__ cz_h,
                       const float* __restrict__ Wq, unsigned short* __restrict__ wq_h,
                       const float* __restrict__ Wk, unsigned short* __restrict__ wk_h) {
    const long MF = (long)MDIM * FDIM;
    int z = blockIdx.z;
    int t = threadIdx.y * 32 + threadIdx.x;                   // 0..255
    if (z < 3) {
        const float* src = zs + (long)z * MF;
        unsigned short* dn = zn + (long)z * MF;
        unsigned short* dt = zt + (long)z * tV;
        __shared__ unsigned short t33[32][33];
        int c0 = blockIdx.x * 32, r0 = blockIdx.y * 32;
        // phase 1: 256 threads x float4 = full 32x32 tile in one shot
        int r = t >> 3, cg = (t & 7) * 4;
        float4 f = *(const float4*)&src[(size_t)(r0 + r) * FDIM + c0 + cg];
        ushort4 u;
        u.x = f2h(f.x); u.y = f2h(f.y); u.z = f2h(f.z); u.w = f2h(f.w);
        *(ushort4*)&dn[(size_t)(r0 + r) * FDIM + c0 + cg] = u;
        t33[r][cg] = u.x; t33[r][cg + 1] = u.y;
        t33[r][cg + 2] = u.z; t33[r][cg + 3] = u.w;
        __syncthreads();
        // phase 2: transposed ushort4 writes along kzT rows
        int tc = t >> 3, ch = (t & 7) * 4;
        ushort4 o;
        o.x = t33[ch][tc]; o.y = t33[ch + 1][tc];
        o.z = t33[ch + 2][tc]; o.w = t33[ch + 3][tc];
        *(ushort4*)&dt[(size_t)(c0 + tc) * MDIM + r0 + ch] = o;
    } else {
        int b = blockIdx.y * gridDim.x + blockIdx.x;          // 0..4095
        if (z == 3) {
            int i = b * 256 + t;                              // NROWS*FDIM/4 = 1,048,576
            float4 f = ((const float4*)cz)[i];
            ushort4 u;
            u.x = f2h(f.x); u.y = f2h(f.y); u.z = f2h(f.z); u.w = f2h(f.w);
            ((ushort4*)cz_h)[i] = u;
        } else if (b < 512) {
            const float4* s = (b < 256) ? (const float4*)Wq : (const float4*)Wk;
            ushort4* d = (b < 256) ? (ushort4*)wq_h : (ushort4*)wk_h;
            int i = (b & 255) * 256 + t;                      // 65536 per matrix
            float4 f = s[i];
            ushort4 u;
            u.x = f2h(f.x); u.y = f2h(f.y); u.z = f2h(f.z); u.w = f2h(f.w);
            d[i] = u;
        }
    }
}

// ---- reduce GWSPLIT fp16 split-K partials; rows<512 -> G fp16 [v][512][512],
//      rows>=512 -> Bfin fp16 [512][1536] (col = v*512+h). Zeroes n2. ----
__global__ void k_rsplit(const unsigned short* __restrict__ GWp,
                         unsigned short* __restrict__ G,
                         unsigned short* __restrict__ Bfin,
                         float* __restrict__ n2, int n) {
    int i = blockIdx.x * blockDim.x + threadIdx.x;
    if (i >= n) return;
    if (i < 3 * NROWS) n2[i] = 0.f;
    int v = i / (1024 * 512);
    int rc = i - v * (1024 * 512);
    int row = rc >> 9, col = rc & 511;
    const unsigned short* p = GWp + (size_t)v * GWSPLIT * 1024 * 512 + rc;
    float s = 0.f;
    #pragma unroll
    for (int sl = 0; sl < GWSPLIT; ++sl) s += h2f(p[(size_t)sl * 1024 * 512]);
    if (row < 512) G[((size_t)v * 512 + row) * 512 + col] = f2h(s);
    else Bfin[(size_t)(row - 512) * 1536 + v * 512 + col] = f2h(s);
}

// ---------------- fp16 GEMM, C[row][col] = sum_k A[row][k]*B[col][k] ----------------
// Tile: 128 x (JT*32); JT=4 (modes 0/3/4) or 2 (MODE2). BK: 64 for modes 0/3/4
// (32KB LDS keeps 4 blocks/CU; r13 showed BK=128 here halves residency = loss),
// 128 for MODE2 (grid-limited to 2/CU either way; halving iters won 10us in r12).
// 256 threads = 4 waves in a 2x2 grid; each wave 4 x JT MFMA tiles of 16x16.
// 1D grid + XCD-aware decode (xcd = blockIdx.x & 7): blocks sharing an operand
// panel / K-slice land on ONE XCD so its 4MB L2 serves the re-reads.
// LDS XOR-swizzle: slot (row,c) holds global chunk (c&8)|((c^row)&7) -> fragment
// ds_read_b128 chunk (kk*4+quad)^(r&7) is 2-way only = free.
// MODE 0: 1024 blk. panel p=(z,y) on xcd p%8; x in-xcd. z=0: Cb=fp16(elu) row-major
//         (q). z>=1: Cb2+(z-1)*cbV = fp16(elu(acc)) TRANSPOSED (k^T) via LDS.
// MODE 2: 512 blk, 128x64 tile, BK=128. q-panel y on xcd y%8, 8 x in-xcd.
//         Cf = CZ + acc, A-frags scaled per (row, view=k/512) from norms.
// MODE 3: 768 blk. K-slice s (24 = 3/xcd) on xcd s%8; slice working set 2MB < L2.
//         Cb16 partial[s] = fp16(acc). view=s>>3, kbeg=(s&7)*K.
// MODE 4: 768 blk. q-panel y on xcd y%8; 12 (x,view) readers co-located.
//         atomicAdd(norms[view][row], sum_col acc*Q[row][col]).
template<int MODE>
__global__ __launch_bounds__(256, 4)
void k_gemm_bt(const unsigned short* __restrict__ A, int lda, long aV, int akmask,
               const unsigned short* __restrict__ B, int ldb, long bV,
               int K,
               unsigned short* __restrict__ Cb, long cbV,
               float* __restrict__ Cf, int ldc, long cfV,
               float* __restrict__ norms,
               const unsigned short* __restrict__ Q,
               const float* __restrict__ CZ,
               const unsigned short* __restrict__ B2,
               unsigned short* __restrict__ Cb2) {
    constexpr int JT  = (MODE == 2) ? 2 : 4;     // j-tiles per wave (cols = JT*32)
    constexpr int BK  = (MODE == 2) ? 128 : 64;  // K per tile
    constexpr int CPR = BK / 8;                  // 16B chunks per row (8 or 16)
    constexpr int RPC = 512 / BK;                // rows covered per g2l16 call (8 or 4)
    constexpr int ACALLS = 128 / RPC / 4;        // A staging calls per wave (4 or 8)
    constexpr int BCALLS = (JT * 32) / RPC / 4;  // B staging calls per wave (4)
    // ---- XCD-aware index decode ----
    const int b = blockIdx.x;
    const int xcd = b & 7, ib = b >> 3;
    int bx, by, z, kbeg = 0, pidx = 0;
    if (MODE == 0) {            // 1024: panels p=0..255 (z=p>>6, y=p&63), x in-xcd
        int p = xcd + 8 * (ib >> 2);
        bx = ib & 3; z = p >> 6; by = p & 63;
    } else if (MODE == 3) {     // 768: slices s=0..23 on xcd s%8, 32 (x,y) in-xcd
        int s = xcd + 8 * (ib >> 5);
        int xy = ib & 31;
        bx = xy & 3; by = xy >> 2;
        z = s >> 3; kbeg = (s & 7) * K; pidx = s;
    } else if (MODE == 4) {     // 768: q-panels y=0..63 on xcd y%8, 12 (x,v) in-xcd
        by = xcd + 8 * (ib / 12);
        int r = ib % 12;
        bx = r & 3; z = r >> 2;
    } else {                    // MODE 2, 512: q-panels y=0..63 on xcd y%8, 8 x in-xcd
        by = xcd + 8 * (ib >> 3);
        bx = ib & 7; z = 0;
    }

    A += (long)z * aV;
    const unsigned short* Bp = (MODE == 0 && z > 0) ? B2 : B;
    Bp += (long)z * bV;

    __shared__ unsigned short S[(MODE == 2) ? (128 * 128 + 64 * 128) : (2 * 128 * 64)];
    unsigned short* As = S;
    unsigned short* Bs = S + 128 * BK;
    const int tid  = threadIdx.x;
    const int lane = tid & 63;
    const int w    = tid >> 6;
    const int wr   = w >> 1, wc = w & 1;
    const int row0 = by * 128;
    const int col0 = bx * (JT * 32);
    const int quad = lane >> 4;
    const int l15  = lane & 15;
    const int srow = lane / CPR;                // row within a staging call
    const int lchunk = lane % CPR;              // 16B chunk within row

    // MODE2: per-row per-view scales for A fragments
    _Float16 sch[3][4];
    if (MODE == 2) {
        #pragma unroll
        for (int v = 0; v < 3; ++v)
            #pragma unroll
            for (int i = 0; i < 4; ++i) {
                int row = row0 + wr * 64 + i * 16 + l15;
                float nn = norms[v * NROWS + row];
                float s = 1.f / fmaxf(sqrtf(fmaxf(nn, 0.f)), 1e-12f);
                sch[v][i] = (_Float16)fminf(s, 60000.f);
            }
    }

    f32x4_t acc[4][JT] = {};

    for (int k0 = kbeg; k0 < kbeg + K; k0 += BK) {
        __syncthreads();
        const int ka = k0 & akmask;
        #pragma unroll
        for (int c = 0; c < ACALLS; ++c) {
            int row = (w * ACALLS + c) * RPC + srow;          // 0..127
            int scol = ((lchunk ^ (row & 7)) & (CPR - 1)) * 8;
            if (CPR == 16) scol = ((lchunk & 8) | ((lchunk ^ row) & 7)) * 8;
            g2l16(A + (size_t)(row0 + row) * lda + ka + scol,
                  &As[(w * ACALLS + c) * 512]);
        }
        #pragma unroll
        for (int c = 0; c < BCALLS; ++c) {
            int row = (w * BCALLS + c) * RPC + srow;          // 0..(JT*32-1)
            int scol = ((lchunk ^ (row & 7)) & (CPR - 1)) * 8;
            if (CPR == 16) scol = ((lchunk & 8) | ((lchunk ^ row) & 7)) * 8;
            g2l16(Bp + (size_t)(col0 + row) * ldb + k0 + scol,
                  &Bs[(w * BCALLS + c) * 512]);
        }
        asm volatile("s_waitcnt vmcnt(0)" ::: "memory");
        __syncthreads();
        #pragma unroll
        for (int kk = 0; kk < BK / 32; ++kk) {
            f16x8_t af[4], bfr[JT];
            #pragma unroll
            for (int i = 0; i < 4; ++i) {
                int r = wr * 64 + i * 16 + l15;
                int ch = (kk * 4 + quad) ^ (r & 7);           // bit3 (BK128) untouched
                af[i] = __builtin_bit_cast(f16x8_t,
                        *(const i32x4_t*)&As[r * BK + ch * 8]);
            }
            if (MODE == 2) {
                int vw = k0 >> 9;
                #pragma unroll
                for (int i = 0; i < 4; ++i) af[i] = af[i] * sch[vw][i];
            }
            #pragma unroll
            for (int j = 0; j < JT; ++j) {
                int r = wc * (JT * 16) + j * 16 + l15;
                int ch = (kk * 4 + quad) ^ (r & 7);
                bfr[j] = __builtin_bit_cast(f16x8_t,
                        *(const i32x4_t*)&Bs[r * BK + ch * 8]);
            }
            #pragma unroll
            for (int i = 0; i < 4; ++i)
                #pragma unroll
                for (int j = 0; j < JT; ++j)
                    acc[i][j] = __builtin_amdgcn_mfma_f32_16x16x32_f16(
                        af[i], bfr[j], acc[i][j], 0, 0, 0);
        }
    }

    // C/D layout (m89-verified): col = lane&15, row = (lane>>4)*4 + reg
    if (MODE == 0) {
        if (z == 0) {
            #pragma unroll
            for (int i = 0; i < 4; ++i) {
                int rb = row0 + wr * 64 + i * 16 + quad * 4;
                #pragma unroll
                for (int j = 0; j < 4; ++j) {
                    int col = col0 + wc * 64 + j * 16 + l15;
                    #pragma unroll
                    for (int r = 0; r < 4; ++r) {
                        float v = acc[i][j][r];
                        v = v > 0.f ? v : expm1f(v);
                        Cb[(size_t)(rb + r) * ldc + col] = f2h(v);
                    }
                }
            }
        } else {
            // transposed epilogue: wave-local 64x64 tile -> LDS (XOR swizzle) -> k^T
            __syncthreads();               // all waves done reading As/Bs
            unsigned short* T = S + w * 4096;   // 8KB slab per wave
            #pragma unroll
            for (int i = 0; i < 4; ++i)
                #pragma unroll
                for (int j = 0; j < 4; ++j) {
                    int ct = j * 16 + l15;
                    #pragma unroll
                    for (int r = 0; r < 4; ++r) {
                        int rt = i * 16 + quad * 4 + r;
                        float v = acc[i][j][r];
                        v = v > 0.f ? v : expm1f(v);
                        T[ct * 64 + (rt ^ ((ct & 7) << 3))] = f2h(v);
                    }
                }
            unsigned short* dst = Cb2 + (long)(z - 1) * cbV;
            #pragma unroll
            for (int it = 0; it < 8; ++it) {
                int c  = it * 8 + (lane >> 3);
                int rg = (lane & 7) * 8;
                i32x4_t val = *(const i32x4_t*)&T[c * 64 + (rg ^ ((c & 7) << 3))];
                *(i32x4_t*)&dst[(size_t)(col0 + wc * 64 + c) * MDIM
                                + row0 + wr * 64 + rg] = val;
            }
        }
    } else if (MODE == 2) {
        #pragma unroll
        for (int i = 0; i < 4; ++i) {
            #pragma unroll
            for (int r = 0; r < 4; ++r) {
                int row = row0 + wr * 64 + i * 16 + quad * 4 + r;
                #pragma unroll
                for (int j = 0; j < JT; ++j) {
                    int col = col0 + wc * (JT * 16) + j * 16 + l15;
                    Cf[(size_t)row * ldc + col] =
                        CZ[(size_t)row * ldc + col] + acc[i][j][r];
                }
            }
        }
    } else if (MODE == 3) {
        unsigned short* C = Cb + (long)pidx * cbV;   // fp16 partial slab
        #pragma unroll
        for (int i = 0; i < 4; ++i) {
            int rb = row0 + wr * 64 + i * 16 + quad * 4;
            #pragma unroll
            for (int j = 0; j < 4; ++j) {
                int col = col0 + wc * 64 + j * 16 + l15;
                #pragma unroll
                for (int r = 0; r < 4; ++r)
                    C[(size_t)(rb + r) * ldc + col] = f2h(acc[i][j][r]);
            }
        }
    } else if (MODE == 4) {
        float* nptr = norms + (long)z * NROWS;
        float rs[4][4] = {};
        #pragma unroll
        for (int i = 0; i < 4; ++i) {
            #pragma unroll
            for (int j = 0; j < 4; ++j) {
                #pragma unroll
                for (int r = 0; r < 4; ++r) {
                    int rb = row0 + wr * 64 + i * 16 + quad * 4;
                    int col = col0 + wc * 64 + j * 16 + l15;
                    rs[i][r] += acc[i][j][r] * h2f(Q[(size_t)(rb + r) * ldc + col]);
                }
            }
        }
        #pragma unroll
        for (int i = 0; i < 4; ++i)
            #pragma unroll
            for (int r = 0; r < 4; ++r) {
                float v = rs[i][r];
                v += __shfl_xor(v, 1);
                v += __shfl_xor(v, 2);
                v += __shfl_xor(v, 4);
                v += __shfl_xor(v, 8);
                if (l15 == 0)
                    atomicAdd(&nptr[row0 + wr * 64 + i * 16 + quad * 4 + r], v);
            }
    }
}

extern "C" void kernel_launch(void* const* d_in, const int* in_sizes, int n_in,
                              void* d_out, int out_size, void* d_ws, size_t ws_size,
                              hipStream_t stream) {
    const float* cz = (const float*)d_in[0];
    const float* zs = (const float*)d_in[1];
    const float* Wq = (const float*)d_in[2];
    const float* Wk = (const float*)d_in[3];
    float* out = (float*)d_out;

    char* ws = (char*)d_ws;
    size_t off = 0;
    auto alloc = [&](size_t bytes) -> void* {
        void* p = ws + off;
        off += (bytes + 255) & ~(size_t)255;
        return p;
    };
    const long MF = (long)MDIM * FDIM;   // 8192*512
    const long KZ = (long)1024 * MDIM;   // per-view kzT stride
    const long PS = (long)1024 * 512;    // partial slab elems

    unsigned short* X_h   = (unsigned short*)alloc((size_t)4 * MF * 2);          // 32 MB: [cz; zv0..2]
    unsigned short* wq_h  = (unsigned short*)alloc((size_t)HDIM * FDIM * 2);
    unsigned short* wk_h  = (unsigned short*)alloc((size_t)HDIM * FDIM * 2);
    unsigned short* q_h   = (unsigned short*)alloc((size_t)NROWS * HDIM * 2);    // 8 MB
    unsigned short* kzT   = (unsigned short*)alloc((size_t)3 * KZ * 2);          // 48 MB: [kT; zvT]/view
    unsigned short* GWp   = (unsigned short*)alloc((size_t)3 * GWSPLIT * PS * 2); // 24 MB fp16 partials
    unsigned short* G     = (unsigned short*)alloc((size_t)3 * 512 * 512 * 2);
    unsigned short* Bfin  = (unsigned short*)alloc((size_t)512 * 1536 * 2);
    float* n2             = (float*)alloc((size_t)3 * NROWS * 4);

    // 1: all input converts + zvT transpose (z=0..2 views, z=3 cz, z=4 Wq/Wk)
    k_prep<<<dim3(FDIM / 32, MDIM / 32, 5), dim3(32, 8), 0, stream>>>(
        zs, X_h + MF, kzT + (size_t)512 * MDIM, KZ,
        cz, X_h, Wq, wq_h, Wk, wk_h);

    // 2: z=0: q = elu(cz@Wq^T) -> q_h; z=1..3: kT_v = elu(zv@Wk^T)^T -> kzT lower half
    k_gemm_bt<0><<<dim3(1024), 256, 0, stream>>>(
        X_h, FDIM, MF, NOMASK, wq_h, FDIM, 0, FDIM,
        q_h, KZ, nullptr, HDIM, 0, nullptr, nullptr, nullptr, wk_h, kzT);

    // 3: [G_v; Wvt_v] = [kT_v; zvT_v] @ kT_v^T, 24 fp16 split-K partial slabs
    k_gemm_bt<3><<<dim3(768), 256, 0, stream>>>(
        kzT, MDIM, KZ, NOMASK, kzT, MDIM, KZ, MDIM / GWSPLIT,
        GWp, PS, nullptr, 512, 0, nullptr, nullptr, nullptr, nullptr, nullptr);

    // 4: reduce partials -> G fp16, Bfin fp16; zero n2
    k_rsplit<<<dim3(3 * 1024 * 512 / 256), 256, 0, stream>>>(
        GWp, G, Bfin, n2, 3 * 1024 * 512);

    // 5: n2_v[r] = (q G_v^T)_r . q_r
    k_gemm_bt<4><<<dim3(768), 256, 0, stream>>>(
        q_h, HDIM, 0, NOMASK, G, HDIM, (long)512 * 512, HDIM,
        nullptr, 0, nullptr, HDIM, 0, n2, q_h, nullptr, nullptr, nullptr);

    // 6: out = cz + sum_v s_v(row) * (q @ Wvt_v^T)   (K=1536, BK=128, A wraps k&511,
    //    per-view per-row scale fused into A fragments; 128x64 tiles, 512 blocks)
    k_gemm_bt<2><<<dim3(512), 256, 0, stream>>>(
        q_h, HDIM, 0, 511, Bfin, 1536, 0, 1536,
        nullptr, 0, out, FDIM, 0, n2, nullptr, cz, nullptr, nullptr);
}